// Round 6
// baseline (1429.298 us; speedup 1.0000x reference)
//
#include <hip/hip_runtime.h>
#include <hip/hip_bf16.h>
#include <math.h>

// Elman RNN. T=256, B=128, INP=HS=OUT=1024.
//  1) cvt_tr: W_ih -> W_ihT bf16 [n][k]  (~10 us)
//  2) fused:  ONE kernel, 4352 blocks x 128 thr:
//       blocks 0..255   = persistent scan (8 m-groups x 32 n-slices, MALL-only
//                         fenceless sync, W_hh slice resident in 64KB LDS,
//                         A-frags loaded DIRECTLY from MALL into regs with
//                         staged vmcnt waits -- no Ht LDS tile).
//       blocks 256..4351 = P-GEMM producers (128x64 tiles of
//                         P = data@W_ih + bias), co-resident on scan CUs'
//                         idle slots (27.6KB LDS <= 160-66.7). Slab-complete
//                         signaled via device-scope atomicAdd(pcnt[mt]);
//                         scan polls pcnt[t]==16 with its h-flags.
//  3) gemm_out: out = h_final @ W_out.T + b_out (fp32)
//
// r4 lesson kept: no placement-dependent branches; all cross-block data goes
// via sc0 sc1 (MALL) or device-scope atomics. Output is deterministic.

typedef __attribute__((ext_vector_type(8))) short bf16x8;
typedef __attribute__((ext_vector_type(4))) float f32x4;
typedef __attribute__((ext_vector_type(4))) unsigned int u32x4;
typedef __attribute__((ext_vector_type(2))) unsigned int u32x2;

#define TT 256
#define BB 128
#define HS 1024
#define H_ELEMS (BB * HS)          // 131072
#define SMEM_BYTES 66688           // max(scan 65536+1152, gemm 18432+9216)

__device__ __forceinline__ short f2bf(float x) {
  __hip_bfloat16 b = __float2bfloat16(x);
  return *reinterpret_cast<short*>(&b);
}
__device__ __forceinline__ float bf2f(unsigned short s) {
  unsigned int u = ((unsigned int)s) << 16;
  float f;
  __builtin_memcpy(&f, &u, 4);
  return f;
}
__device__ __forceinline__ float fast_exp2(float x) {
#if __has_builtin(__builtin_amdgcn_exp2f)
  return __builtin_amdgcn_exp2f(x);
#else
  return exp2f(x);
#endif
}
__device__ __forceinline__ float fast_rcp(float x) {
#if __has_builtin(__builtin_amdgcn_rcpf)
  return __builtin_amdgcn_rcpf(x);
#else
  return 1.0f / x;
#endif
}
__device__ __forceinline__ float fast_tanh(float x) {
  float xc = fminf(fmaxf(x, -9.0f), 9.0f);
  float e = fast_exp2(2.8853900817779268f * xc);
  return (e - 1.0f) * fast_rcp(e + 1.0f);
}

// ---- MALL-direct (sc0 sc1) ops: coherence-point, placement-independent ----
__device__ __forceinline__ void mall_load_bf8(bf16x8* dst, const void* p) {
  asm volatile("global_load_dwordx4 %0, %1, off sc0 sc1" : "=v"(*dst) : "v"(p) : "memory");
}
__device__ __forceinline__ void mall_load_u16(unsigned* dst, const void* p) {
  asm volatile("global_load_ushort %0, %1, off sc0 sc1" : "=v"(*dst) : "v"(p) : "memory");
}
__device__ __forceinline__ void mall_store_b128(void* p, u32x4 v) {
  asm volatile("global_store_dwordx4 %0, %1, off sc0 sc1" :: "v"(p), "v"(v) : "memory");
}
__device__ __forceinline__ void mall_store_b64(void* p, u32x2 v) {
  asm volatile("global_store_dwordx2 %0, %1, off sc0 sc1" :: "v"(p), "v"(v) : "memory");
}
__device__ __forceinline__ void mall_store_b32(void* p, unsigned v) {
  asm volatile("global_store_dword %0, %1, off sc0 sc1" :: "v"(p), "v"(v) : "memory");
}
__device__ __forceinline__ unsigned mall_poll_b32(const void* p) {
  unsigned v;
  asm volatile("global_load_dword %0, %1, off sc0 sc1" : "=v"(v) : "v"(p) : "memory");
  asm volatile("s_waitcnt vmcnt(0)" : "+v"(v));
  return v;
}
__device__ __forceinline__ void wait_vm0() {
  asm volatile("s_waitcnt vmcnt(0)" ::: "memory");
}
#define WAITV(N) asm volatile("s_waitcnt vmcnt(" #N ")" ::: "memory")
__device__ __forceinline__ void tie8(bf16x8& a, bf16x8& b, bf16x8& c, bf16x8& d,
                                     bf16x8& e, bf16x8& f, bf16x8& g, bf16x8& h) {
  asm volatile("" : "+v"(a), "+v"(b), "+v"(c), "+v"(d),
                    "+v"(e), "+v"(f), "+v"(g), "+v"(h));
}
__device__ __forceinline__ void tie4u(unsigned& a, unsigned& b, unsigned& c, unsigned& d) {
  asm volatile("" : "+v"(a), "+v"(b), "+v"(c), "+v"(d));
}

// ---------------------------------------------------------------------------
// cvt_tr: W_ihT[n][k] = bf16(W_ih[k][n]). 64x64 LDS tiles, grid (16,16).
// ---------------------------------------------------------------------------
__global__ __launch_bounds__(256) void cvt_tr(const float* __restrict__ src,
                                              __hip_bfloat16* __restrict__ dst) {
  __shared__ __hip_bfloat16 T[64][72];
  const int tid = threadIdx.x;
  const int k0 = blockIdx.y * 64, n0 = blockIdx.x * 64;
  const int r = tid >> 4, c4 = (tid & 15) * 4;
#pragma unroll
  for (int p = 0; p < 4; ++p) {
    int kk = r + p * 16;
    f32x4 v = *reinterpret_cast<const f32x4*>(src + (size_t)(k0 + kk) * 1024 + n0 + c4);
#pragma unroll
    for (int j = 0; j < 4; ++j) T[c4 + j][kk] = __float2bfloat16(v[j]);
  }
  __syncthreads();
  const int rr = tid >> 3, u = tid & 7;
#pragma unroll
  for (int p = 0; p < 2; ++p) {
    int R = rr + p * 32;
    *reinterpret_cast<bf16x8*>(dst + (size_t)(n0 + R) * 1024 + k0 + u * 8) =
        *reinterpret_cast<const bf16x8*>(&T[R][u * 8]);
  }
}

// ---------------------------------------------------------------------------
// fused: scan blocks (0..255) + P-GEMM producer blocks (256..4351).
// ---------------------------------------------------------------------------
__global__ __launch_bounds__(128) void fused(
    const float* __restrict__ data,            // [32768][1024] fp32
    const __hip_bfloat16* __restrict__ W_ihT,  // [1024][1024] bf16 [n][k]
    const float* __restrict__ W_hh,            // [1024][1024] fp32 [k][n]
    const float* __restrict__ b_i,
    const float* __restrict__ b_h,
    __hip_bfloat16* __restrict__ P,            // [256][131072] bf16
    __hip_bfloat16* __restrict__ hbuf,         // [2][131072] bf16, pre-zeroed
    unsigned* __restrict__ flags,              // [8][32], pre-zeroed
    unsigned* __restrict__ pcnt) {             // [256], pre-zeroed
  __shared__ __attribute__((aligned(16))) unsigned char smem[SMEM_BYTES];
  const int tid = threadIdx.x;
  const int w = tid >> 6, lane = tid & 63;
  const int quad = lane >> 4, l16 = lane & 15;

  if (blockIdx.x >= 256) {
    // ================= P-GEMM producer: 128M x 64N tile =================
    auto As = (__hip_bfloat16(*)[72])(smem);            // 128 x 72
    auto Bs = (__hip_bfloat16(*)[72])(smem + 18432);    // 64 x 72
    const int j = (int)blockIdx.x - 256;
    const int mt = j >> 4, nt = j & 15;                 // slab mt = t index
    const int m0g = mt * 128, n0g = nt * 64;
    const int sr = tid >> 3, su = tid & 7;

    float bias[4];
#pragma unroll
    for (int ni = 0; ni < 4; ++ni) {
      int c = n0g + ni * 16 + l16;
      bias[ni] = b_i[c] + b_h[c];
    }

    f32x4 acc[4][4] = {};
    for (int k0 = 0; k0 < 1024; k0 += 64) {
      __syncthreads();
#pragma unroll
      for (int p = 0; p < 8; ++p) {
        int row = sr + p * 16;
        const float* ap = data + (size_t)(m0g + row) * 1024 + k0 + su * 8;
        f32x4 x = *reinterpret_cast<const f32x4*>(ap);
        f32x4 y = *reinterpret_cast<const f32x4*>(ap + 4);
        bf16x8 av;
        av[0] = f2bf(x[0]); av[1] = f2bf(x[1]); av[2] = f2bf(x[2]); av[3] = f2bf(x[3]);
        av[4] = f2bf(y[0]); av[5] = f2bf(y[1]); av[6] = f2bf(y[2]); av[7] = f2bf(y[3]);
        *reinterpret_cast<bf16x8*>(&As[row][su * 8]) = av;
      }
#pragma unroll
      for (int p = 0; p < 4; ++p) {
        int n = sr + p * 16;
        *reinterpret_cast<bf16x8*>(&Bs[n][su * 8]) = *reinterpret_cast<const bf16x8*>(
            W_ihT + (size_t)(n0g + n) * 1024 + k0 + su * 8);
      }
      __syncthreads();
#pragma unroll
      for (int kk = 0; kk < 2; ++kk) {
        bf16x8 af[4], bfr[4];
#pragma unroll
        for (int mi = 0; mi < 4; ++mi)
          af[mi] = *reinterpret_cast<const bf16x8*>(&As[w * 64 + mi * 16 + l16][kk * 32 + quad * 8]);
#pragma unroll
        for (int ni = 0; ni < 4; ++ni)
          bfr[ni] = *reinterpret_cast<const bf16x8*>(&Bs[ni * 16 + l16][kk * 32 + quad * 8]);
#pragma unroll
        for (int mi = 0; mi < 4; ++mi)
#pragma unroll
          for (int ni = 0; ni < 4; ++ni)
            acc[mi][ni] = __builtin_amdgcn_mfma_f32_16x16x32_bf16(af[mi], bfr[ni], acc[mi][ni], 0, 0, 0);
      }
    }
    __syncthreads();
    // restage C (+bias, bf16) into As, then vectorized MALL stores
#pragma unroll
    for (int mi = 0; mi < 4; ++mi)
#pragma unroll
      for (int ni = 0; ni < 4; ++ni)
#pragma unroll
        for (int r = 0; r < 4; ++r)
          As[w * 64 + mi * 16 + quad * 4 + r][ni * 16 + l16] =
              __float2bfloat16(acc[mi][ni][r] + bias[ni]);
    __syncthreads();
    {
      __hip_bfloat16* Prow = P + (size_t)(m0g + tid) * 1024 + n0g;
#pragma unroll
      for (int s = 0; s < 8; ++s) {
        u32x4 v = *reinterpret_cast<const u32x4*>(&As[tid][s * 8]);
        mall_store_b128(Prow + s * 8, v);
      }
      wait_vm0();   // P tile acked at MALL
    }
    __syncthreads();
    if (tid == 0) atomicAdd(pcnt + mt, 1u);  // device-scope, executes at MALL
    return;
  }

  // ================= persistent scan =================
  __hip_bfloat16* Wt = (__hip_bfloat16*)smem;             // [32][1024] swizzled
  __hip_bfloat16* Cs = (__hip_bfloat16*)(smem + 65536);   // [16][36] staging
  const int m = blockIdx.x & 7;
  const int ng = blockIdx.x >> 3;
  const int m0 = m * 16, n0 = ng * 32;

  // Resident W slice: Wt[nl][k] = W_hh[k][n0+nl]; swizzle sg=(k>>3)^(nl&7).
  for (int i = tid; i < 32 * 1024 / 4; i += 128) {
    int nq = i & 7, k = i >> 3;
    f32x4 v = *reinterpret_cast<const f32x4*>(W_hh + (size_t)k * 1024 + n0 + nq * 4);
#pragma unroll
    for (int jj = 0; jj < 4; ++jj) {
      int nl2 = nq * 4 + jj;
      int sg = (k >> 3) ^ (nl2 & 7);
      Wt[nl2 * 1024 + sg * 8 + (k & 7)] = __float2bfloat16(v[jj]);
    }
  }
  __syncthreads();

  const int nl = w * 16 + l16;
  const int col = n0 + nl;
  const int crow = tid >> 3, cseg = tid & 7;
  unsigned* gflags = flags + m * 32;

  for (int t = 0; t < TT; ++t) {
    const __hip_bfloat16* hc = hbuf + (size_t)(t & 1) * H_ELEMS;
    __hip_bfloat16* hn = hbuf + (size_t)((t + 1) & 1) * H_ELEMS;

    // ---- gate: 32 h-flags (>=t; trivially true at t=0) + P slab counter ----
    if (tid < 33) {
      const unsigned* fp = (tid < 32) ? (gflags + tid) : (pcnt + t);
      unsigned tgt = (tid < 32) ? (unsigned)t : 16u;
      int g = 0;
      while (mall_poll_b32(fp) < tgt && ++g < (1 << 20)) {}
    }
    __syncthreads();

    // ---- issue P_t (4 x u16) + 32 A-frag b128 MALL loads ----
    const __hip_bfloat16* Pt =
        P + (size_t)t * H_ELEMS + (size_t)(m0 + quad * 4) * 1024 + col;
    unsigned pv0, pv1, pv2, pv3;
    mall_load_u16(&pv0, Pt);
    mall_load_u16(&pv1, Pt + 1024);
    mall_load_u16(&pv2, Pt + 2048);
    mall_load_u16(&pv3, Pt + 3072);
    const __hip_bfloat16* hrow = hc + (size_t)(m0 + l16) * 1024 + quad * 8;
    bf16x8 fr[8][4];
#pragma unroll
    for (int c = 0; c < 8; ++c)
#pragma unroll
      for (int jj = 0; jj < 4; ++jj)
        mall_load_bf8(&fr[c][jj], hrow + c * 128 + jj * 32);

    // ---- MFMA with staged waits: pipeline MALL transfer vs compute ----
    f32x4 acc[4] = {{0.f, 0.f, 0.f, 0.f}, {0.f, 0.f, 0.f, 0.f},
                    {0.f, 0.f, 0.f, 0.f}, {0.f, 0.f, 0.f, 0.f}};
#pragma unroll
    for (int cc = 0; cc < 4; ++cc) {
      if (cc == 0) { WAITV(24); tie8(fr[0][0], fr[0][1], fr[0][2], fr[0][3],
                                     fr[1][0], fr[1][1], fr[1][2], fr[1][3]); }
      else if (cc == 1) { WAITV(16); tie8(fr[2][0], fr[2][1], fr[2][2], fr[2][3],
                                          fr[3][0], fr[3][1], fr[3][2], fr[3][3]); }
      else if (cc == 2) { WAITV(8); tie8(fr[4][0], fr[4][1], fr[4][2], fr[4][3],
                                         fr[5][0], fr[5][1], fr[5][2], fr[5][3]); }
      else { WAITV(0); tie8(fr[6][0], fr[6][1], fr[6][2], fr[6][3],
                            fr[7][0], fr[7][1], fr[7][2], fr[7][3]);
             tie4u(pv0, pv1, pv2, pv3); }
#pragma unroll
      for (int h2 = 0; h2 < 2; ++h2) {
        int c = cc * 2 + h2;
#pragma unroll
        for (int jj = 0; jj < 4; ++jj) {
          int G = c * 16 + jj * 4 + quad;
          int sg = G ^ (nl & 7);
          bf16x8 bfrag = *reinterpret_cast<const bf16x8*>(&Wt[nl * 1024 + sg * 8]);
          acc[jj] = __builtin_amdgcn_mfma_f32_16x16x32_bf16(fr[c][jj], bfrag, acc[jj], 0, 0, 0);
        }
      }
    }

    // ---- epilogue: sum, +P, tanh -> stage (transpose) -> MALL store ----
    unsigned pvv[4] = {pv0, pv1, pv2, pv3};
#pragma unroll
    for (int r = 0; r < 4; ++r) {
      float s = (acc[0][r] + acc[1][r]) + (acc[2][r] + acc[3][r]) +
                bf2f((unsigned short)pvv[r]);
      Cs[(quad * 4 + r) * 36 + nl] = __float2bfloat16(fast_tanh(s));
    }
    __syncthreads();
    {
      u32x2 val = *reinterpret_cast<const u32x2*>(&Cs[crow * 36 + cseg * 4]);
      mall_store_b64(hn + (size_t)(m0 + crow) * 1024 + n0 + cseg * 4, val);
      wait_vm0();  // h stores acked at MALL before flag
    }
    __syncthreads();  // both waves drained

    if (t != TT - 1 && tid == 0)
      mall_store_b32(gflags + ng, (unsigned)(t + 1));
  }
}

// ---------------------------------------------------------------------------
// gemm_out: out = h_final @ W_out.T + b_out.  (unchanged, validated)
// ---------------------------------------------------------------------------
__global__ __launch_bounds__(256) void gemm_out(
    const __hip_bfloat16* __restrict__ h,   // [128][1024] (hbuf slot 0)
    const float* __restrict__ W_out,        // [1024][1024] row-major [o][k]
    const float* __restrict__ b_out,
    float* __restrict__ out) {              // [128][1024] fp32
  const int tid = threadIdx.x;
  const int wave = tid >> 6, lane = tid & 63;
  const int quad = lane >> 4, l16 = lane & 15;
  const int o = blockIdx.x * 64 + wave * 16 + l16;

  f32x4 acc[8] = {};
  for (int k0 = 0; k0 < 1024; k0 += 32) {
    f32x4 w0 = *reinterpret_cast<const f32x4*>(W_out + (size_t)o * 1024 + k0 + quad * 8);
    f32x4 w1 = *reinterpret_cast<const f32x4*>(W_out + (size_t)o * 1024 + k0 + quad * 8 + 4);
    bf16x8 bfr;
    bfr[0] = f2bf(w0[0]); bfr[1] = f2bf(w0[1]); bfr[2] = f2bf(w0[2]); bfr[3] = f2bf(w0[3]);
    bfr[4] = f2bf(w1[0]); bfr[5] = f2bf(w1[1]); bfr[6] = f2bf(w1[2]); bfr[7] = f2bf(w1[3]);
#pragma unroll
    for (int mi = 0; mi < 8; ++mi) {
      bf16x8 af = *reinterpret_cast<const bf16x8*>(h + (size_t)(mi * 16 + l16) * 1024 + k0 + quad * 8);
      acc[mi] = __builtin_amdgcn_mfma_f32_16x16x32_bf16(af, bfr, acc[mi], 0, 0, 0);
    }
  }
  const float bias = b_out[o];
#pragma unroll
  for (int mi = 0; mi < 8; ++mi)
#pragma unroll
    for (int r = 0; r < 4; ++r)
      out[(size_t)(mi * 16 + quad * 4 + r) * 1024 + o] = acc[mi][r] + bias;
}

// ---------------------------------------------------------------------------
// Workspace: [0,64MB) P bf16 | +512KB h dbuf | +1KB flags | +1KB pcnt | +2MB W_ihT
// ---------------------------------------------------------------------------
extern "C" void kernel_launch(void* const* d_in, const int* in_sizes, int n_in,
                              void* d_out, int out_size, void* d_ws, size_t ws_size,
                              hipStream_t stream) {
  const float* data  = (const float*)d_in[0];
  const float* W_ih  = (const float*)d_in[1];
  const float* W_hh  = (const float*)d_in[2];
  const float* b_i   = (const float*)d_in[3];
  const float* b_h   = (const float*)d_in[4];
  const float* W_out = (const float*)d_in[5];
  const float* b_out = (const float*)d_in[6];
  float* out = (float*)d_out;

  char* ws = (char*)d_ws;
  const size_t OFF_P   = 0;
  const size_t OFF_H   = (size_t)TT * H_ELEMS * 2;        // 67,108,864
  const size_t OFF_FLG = OFF_H + 2 * H_ELEMS * 2;         // +524,288
  const size_t OFF_PC  = OFF_FLG + 1024;
  const size_t OFF_WT  = OFF_PC + 1024;                   // W_ihT, 2MB

  __hip_bfloat16* P     = (__hip_bfloat16*)(ws + OFF_P);
  __hip_bfloat16* hbuf  = (__hip_bfloat16*)(ws + OFF_H);
  unsigned* flags       = (unsigned*)(ws + OFF_FLG);
  unsigned* pcnt        = (unsigned*)(ws + OFF_PC);
  __hip_bfloat16* W_ihT = (__hip_bfloat16*)(ws + OFF_WT);

  // zero h0/h1 + flags + pcnt (ws is poisoned 0xAA before every launch)
  hipMemsetAsync(ws + OFF_H, 0, 2 * H_ELEMS * 2 + 2048, stream);

  cvt_tr<<<dim3(16, 16), 256, 0, stream>>>(W_ih, W_ihT);
  fused<<<256 + 4096, 128, 0, stream>>>(data, W_ihT, W_hh, b_i, b_h,
                                        P, hbuf, flags, pcnt);
  gemm_out<<<16, 256, 0, stream>>>(hbuf, W_out, b_out, out);  // h[256] in slot 0
}